// Round 1
// baseline (40.823 us; speedup 1.0000x reference)
//
#include <hip/hip_runtime.h>

// out[b, n*7+c, w] = sum_k x[b, w*3+k-21, c] * kern[n, k]   (n in 0..72)
// out[b, 511,   w] = sum_k x[b, w*3+k-21, 0] * kern[73, k]
// x zero-padded for s < 0.  Output shape (32, 512, 2736), fp32.

constexpr int Bn    = 32;
constexpr int Sn    = 8192;
constexpr int Cn    = 7;
constexpr int Kn    = 8;
constexpr int NKn   = 74;
constexpr int PADn  = 21;
constexpr int Wn    = 2736;          // (8192 + 21 - 8)/3 + 1
constexpr int OCH   = 512;           // 73*7 + 1
constexpr int WTILE = 256;
constexpr int NGROUP = 4;
constexpr int NSAMP = (WTILE - 1) * 3 + Kn;   // 773 samples per tile
constexpr int XTILE = NSAMP * Cn;             // 5411 floats (21.6 KB)

__global__ __launch_bounds__(256)
void strided_conv_kernel(const float* __restrict__ x,
                         const float* __restrict__ kern,
                         float* __restrict__ out) {
    __shared__ float lx[XTILE];
    __shared__ float lk[NKn * Kn];

    const int tid = threadIdx.x;
    const int w0  = blockIdx.x * WTILE;
    const int b   = blockIdx.y;
    const int g   = blockIdx.z;

    // ---- stage x tile: contiguous region of batch b starting at sample w0*3-21
    const int sbase7 = (w0 * 3 - PADn) * Cn;       // float offset within batch (may be <0)
    const float* xb = x + (size_t)b * (Sn * Cn);
    for (int i = tid; i < XTILE; i += 256) {
        int off = sbase7 + i;
        lx[i] = (off >= 0 && off < Sn * Cn) ? xb[off] : 0.0f;
    }
    // ---- stage kernels
    for (int i = tid; i < NKn * Kn; i += 256) lk[i] = kern[i];
    __syncthreads();

    const int w = w0 + tid;
    if (w >= Wn) return;

    // ---- window into registers: win[c][k] = x[b, w*3+k-21, c]
    float win[Cn][Kn];
#pragma unroll
    for (int k = 0; k < Kn; ++k) {
        const int base = (tid * 3 + k) * Cn;   // (21t + 7k) — stride 21 mod 32 is conflict-free
#pragma unroll
        for (int c = 0; c < Cn; ++c) win[c][k] = lx[base + c];
    }

    const int n0 = (73 * g) / NGROUP;
    const int n1 = (73 * (g + 1)) / NGROUP;
    float* ob = out + (size_t)b * OCH * Wn + w;

    for (int n = n0; n < n1; ++n) {
        float kn[Kn];
#pragma unroll
        for (int k = 0; k < Kn; ++k) kn[k] = lk[n * Kn + k];
#pragma unroll
        for (int c = 0; c < Cn; ++c) {
            float acc = 0.0f;
#pragma unroll
            for (int k = 0; k < Kn; ++k) acc = fmaf(win[c][k], kn[k], acc);
            ob[(size_t)(n * 7 + c) * Wn] = acc;
        }
    }
    if (g == NGROUP - 1) {
        float acc = 0.0f;
#pragma unroll
        for (int k = 0; k < Kn; ++k) acc = fmaf(win[0][k], lk[73 * Kn + k], acc);
        ob[(size_t)511 * Wn] = acc;
    }
}

extern "C" void kernel_launch(void* const* d_in, const int* in_sizes, int n_in,
                              void* d_out, int out_size, void* d_ws, size_t ws_size,
                              hipStream_t stream) {
    const float* x    = (const float*)d_in[0];
    const float* kern = (const float*)d_in[1];
    float* out        = (float*)d_out;

    dim3 grid((Wn + WTILE - 1) / WTILE, Bn, NGROUP);   // 11 x 32 x 4
    dim3 block(256);
    strided_conv_kernel<<<grid, block, 0, stream>>>(x, kern, out);
}